// Round 5
// baseline (1746.818 us; speedup 1.0000x reference)
//
#include <hip/hip_runtime.h>
#include <cstdint>
#include <cstddef>

// DCGN collapse: adjacency == identity exactly, attn_pool dead. Two stages:
//   Stage1: H[8192,1100] = lrelu(nc(x,w1) @ W1 + b1), K=2048
//   Stage2: out[2048,512] = lrelu(nc(H,w2) @ W2 + b2), K=1100
// Inputs PROVEN f32 (round-4 A/B: bf16 interpretation NaNs, f32 finite).
// Output now f32 (reference output dtype per harness doc; bf16 writes gave
// error == max|ref| signature). H intermediate bf16. Probe kept as guard.

using u16 = unsigned short;
using u32 = unsigned int;
using floatx4 = __attribute__((ext_vector_type(4))) float;
using shortx8 = __attribute__((ext_vector_type(8))) short;

#define OUT_MODE 1   // 0 = bf16 output, 1 = f32 output

__device__ __forceinline__ float bf_lo(u32 u) { return __uint_as_float(u << 16); }
__device__ __forceinline__ float bf_hi(u32 u) { return __uint_as_float(u & 0xffff0000u); }
__device__ __forceinline__ float bf2f(u16 s) { return __uint_as_float(((u32)s) << 16); }
__device__ __forceinline__ u16 f2bf(float f) {
  u32 u = __float_as_uint(f);
  u += 0x7fffu + ((u >> 16) & 1u);   // RNE
  return (u16)(u >> 16);
}

__device__ __forceinline__ float ld_elem(const void* b, size_t i, int isf32) {
  return isf32 ? ((const float*)b)[i] : bf2f(((const u16*)b)[i]);
}
__device__ __forceinline__ void ld8(const void* b, size_t i, int isf32, float* o) {
  if (isf32) {
    const float* p = (const float*)b + i;
    float4 a = *(const float4*)p, c = *(const float4*)(p + 4);
    o[0]=a.x; o[1]=a.y; o[2]=a.z; o[3]=a.w; o[4]=c.x; o[5]=c.y; o[6]=c.z; o[7]=c.w;
  } else {
    const u16* p = (const u16*)b + i;
    uint2 a = *(const uint2*)p, c = *(const uint2*)(p + 4);
    o[0]=bf_lo(a.x); o[1]=bf_hi(a.x); o[2]=bf_lo(a.y); o[3]=bf_hi(a.y);
    o[4]=bf_lo(c.x); o[5]=bf_hi(c.x); o[6]=bf_lo(c.y); o[7]=bf_hi(c.y);
  }
}

// dtype probe: bits 14:7 = low-bf16 exponent (concentrated for N(0,1) bf16
// pairs) vs f32 mantissa bits (uniform). flag=1 => f32.
__global__ __launch_bounds__(256) void dtype_probe(const u32* __restrict__ x,
                                                   int* __restrict__ flag) {
  __shared__ int cnt[256];
  int t = threadIdx.x, c = 0;
  for (int i = t; i < 1024; i += 256) {
    u32 e = (x[i] >> 7) & 0xFFu;
    c += (e >= 110u && e <= 134u) ? 1 : 0;
  }
  cnt[t] = c;
  __syncthreads();
  for (int s = 128; s > 0; s >>= 1) {
    if (t < s) cnt[t] += cnt[t + s];
    __syncthreads();
  }
  if (t == 0) *flag = (cnt[0] < 512) ? 1 : 0;
}

// C[m,n] = lrelu( sum_k (sum_p X[xoff + (4m+p)*K + k]*Wc[p,k]) * W[k,n] + bias[n] )
// modes: 0=bf16, 1=f32, 2=follow device flag. xoff/coff are ELEMENT offsets.
template <int BM, int BN>
__global__ __launch_bounds__(256) void fused_nc_gemm(
    const void* __restrict__ X, const void* __restrict__ Wc,
    const void* __restrict__ W, const void* __restrict__ bias,
    void* __restrict__ C, int Nn, int K,
    size_t xoff, size_t coff,
    const int* __restrict__ dflag, int xmode, int wmode, int omode)
{
  constexpr int BK = 32;
  constexpr int WTM = BM / 2, WTN = BN / 2;
  constexpr int MI = WTM / 16, NI = WTN / 16;
  __shared__ u16 As[4 * BM * 8];
  __shared__ u16 Bs[4 * BN * 8];

  int fl = (xmode == 2 || wmode == 2 || omode == 2) ? *dflag : 0;
  int xf32 = (xmode == 2) ? fl : xmode;
  int wf32 = (wmode == 2) ? fl : wmode;
  int of32 = (omode == 2) ? fl : omode;

  int tid = threadIdx.x;
  int lane = tid & 63, wave = tid >> 6;
  int m0 = blockIdx.y * BM, n0 = blockIdx.x * BN;
  int wrow = (wave >> 1) * WTM, wcol = (wave & 1) * WTN;
  int quad = lane >> 4, lm = lane & 15;

  floatx4 acc[MI][NI] = {};

  int kiters = (K + BK - 1) / BK;
  for (int it = 0; it < kiters; ++it) {
    int k0 = it * BK;
    // ---- A staging: nodeconv on the fly; octet = (row, 8 consecutive k) ----
    for (int idx = tid; idx < BM * 4; idx += 256) {
      int row = idx >> 2, kc = idx & 3;
      int gk = k0 + kc * 8;
      size_t xbase = xoff + ((size_t)(4 * (m0 + row))) * K + gk;
      float a[8] = {0.f, 0.f, 0.f, 0.f, 0.f, 0.f, 0.f, 0.f};
      if (gk + 8 <= K) {
#pragma unroll
        for (int p = 0; p < 4; ++p) {
          float xv[8], wv[8];
          ld8(X, xbase + (size_t)p * K, xf32, xv);
          ld8(Wc, (size_t)p * K + gk, wf32, wv);
#pragma unroll
          for (int j = 0; j < 8; ++j) a[j] += xv[j] * wv[j];
        }
      } else {
        for (int j = 0; j < 8; ++j) {
          if (gk + j < K) {
            float s = 0.f;
#pragma unroll
            for (int p = 0; p < 4; ++p)
              s += ld_elem(X, xbase + (size_t)p * K + j, xf32) *
                   ld_elem(Wc, (size_t)p * K + gk + j, wf32);
            a[j] = s;
          }
        }
      }
      u32 o0 = (u32)f2bf(a[0]) | ((u32)f2bf(a[1]) << 16);
      u32 o1 = (u32)f2bf(a[2]) | ((u32)f2bf(a[3]) << 16);
      u32 o2 = (u32)f2bf(a[4]) | ((u32)f2bf(a[5]) << 16);
      u32 o3 = (u32)f2bf(a[6]) | ((u32)f2bf(a[7]) << 16);
      uint4 ov; ov.x = o0; ov.y = o1; ov.z = o2; ov.w = o3;
      *(uint4*)&As[(kc * BM + row) * 8] = ov;    // ds_write_b128
    }
    // ---- B staging from W[K,N]: octet = (fixed n, 8 consecutive k) ----
    for (int idx = tid; idx < BN * 4; idx += 256) {
      int n = idx % BN, kq = idx / BN;
      int gn = n0 + n;
      u16 tmp[8];
      if (gn < Nn) {
#pragma unroll
        for (int j = 0; j < 8; ++j) {
          int gk = k0 + kq * 8 + j;
          tmp[j] = (gk < K) ? f2bf(ld_elem(W, (size_t)gk * Nn + gn, wf32)) : (u16)0;
        }
      } else {
#pragma unroll
        for (int j = 0; j < 8; ++j) tmp[j] = (u16)0;
      }
      u32 o0 = (u32)tmp[0] | ((u32)tmp[1] << 16);
      u32 o1 = (u32)tmp[2] | ((u32)tmp[3] << 16);
      u32 o2 = (u32)tmp[4] | ((u32)tmp[5] << 16);
      u32 o3 = (u32)tmp[6] | ((u32)tmp[7] << 16);
      uint4 ov; ov.x = o0; ov.y = o1; ov.z = o2; ov.w = o3;
      *(uint4*)&Bs[(kq * BN + n) * 8] = ov;      // ds_write_b128
    }
    __syncthreads();

    shortx8 av[MI], bv[NI];
#pragma unroll
    for (int mi = 0; mi < MI; ++mi)
      av[mi] = *(const shortx8*)&As[((size_t)(quad * BM + wrow + mi * 16 + lm)) * 8];
#pragma unroll
    for (int ni = 0; ni < NI; ++ni)
      bv[ni] = *(const shortx8*)&Bs[((size_t)(quad * BN + wcol + ni * 16 + lm)) * 8];
#pragma unroll
    for (int mi = 0; mi < MI; ++mi)
#pragma unroll
      for (int ni = 0; ni < NI; ++ni)
        acc[mi][ni] = __builtin_amdgcn_mfma_f32_16x16x32_bf16(av[mi], bv[ni], acc[mi][ni], 0, 0, 0);
    __syncthreads();
  }

  // ---- epilogue: bias + leaky_relu; C/D map col=lane&15, row=quad*4+reg ----
#pragma unroll
  for (int ni = 0; ni < NI; ++ni) {
    int gn = n0 + wcol + ni * 16 + lm;
    if (gn >= Nn) continue;
    float bb = ld_elem(bias, gn, wf32);
#pragma unroll
    for (int mi = 0; mi < MI; ++mi) {
#pragma unroll
      for (int r = 0; r < 4; ++r) {
        int gm = m0 + wrow + mi * 16 + quad * 4 + r;
        float v = acc[mi][ni][r] + bb;
        v = (v >= 0.f) ? v : 0.01f * v;
        size_t ci = coff + (size_t)gm * Nn + gn;
        if (of32) ((float*)C)[ci] = v;
        else      ((u16*)C)[ci]   = f2bf(v);
      }
    }
  }
}

extern "C" void kernel_launch(void* const* d_in, const int* in_sizes, int n_in,
                              void* d_out, int out_size, void* d_ws, size_t ws_size,
                              hipStream_t stream) {
  const void* x  = d_in[0];   // [32768,2048]
  const void* w1 = d_in[1];   // [4,2048]
  const void* W1 = d_in[4];   // [2048,1100]
  const void* b1 = d_in[5];   // [1100]
  const void* w2 = d_in[6];   // [4,1100]
  const void* W2 = d_in[9];   // [1100,512]
  const void* b2 = d_in[10];  // [512]

  int* dflag = (int*)d_ws;
  u16* Hc = (u16*)((char*)d_ws + 256);   // H chunk: [4*SM, 1100] bf16

  dtype_probe<<<1, 256, 0, stream>>>((const u32*)x, dflag);

  int SM = 2048;   // out-rows per chunk; shrink until H chunk fits ws
  while (SM > 64 && (size_t)SM * 4 * 1100 * 2 + 256 > ws_size) SM >>= 1;

  for (int m0 = 0; m0 < 2048; m0 += SM) {
    // stage 1: Hc[0:4*SM,1100] = lrelu(nc(x rows 16*m0..,w1) @ W1 + b1), K=2048
    fused_nc_gemm<128, 128><<<dim3(9, (4 * SM) / 128), 256, 0, stream>>>(
        x, w1, W1, b1, Hc, 1100, 2048,
        (size_t)(16 * m0) * 2048, 0, dflag, 2, 2, 0);
    // stage 2: out[m0:m0+SM,512] = lrelu(nc(Hc,w2) @ W2 + b2), K=1100
    fused_nc_gemm<64, 64><<<dim3(8, SM / 64), 256, 0, stream>>>(
        Hc, w2, W2, b2, d_out, 512, 1100,
        0, (size_t)m0 * 512, dflag, 0, 2, OUT_MODE);
  }
}